// Round 1
// baseline (7654.918 us; speedup 1.0000x reference)
//
#include <hip/hip_runtime.h>
#include <stdint.h>

#define H_  128
#define L_  512
#define B_  512
#define A_  16
#define G3_ 384

// ---------------- workspace layout (bytes) ----------------
#define OFF_M1    0          // f16 [384][128]  enc: Wih@enc_emb_W
#define OFF_WHHE  98304      // f16 [384][128]  enc_Whh
#define OFF_WB    196608     // f16 [512][128]  attn_W[:,128:]
#define OFF_WIH   327680     // f16 [384][128]  dec_Wih
#define OFF_WHH   425984     // f16 [384][128]  dec_Whh
#define OFF_WC2   524288     // f16 [128][128]  comb_W[:,128:]
#define OFF_PA    557056     // f16 [512][16]   Wa@dec_emb_W
#define OFF_PC    573440     // f16 [128][16]   Wc1@dec_emb_W
#define OFF_OUTW  577536     // f16 [16][128]
#define OFF_BGI   581632     // f32 [384]  bih + Wih@enc_emb_b
#define OFF_ZB    583168     // f32 [512]  attn_b + Wa@dec_emb_b
#define OFF_OB    585216     // f32 [128]  comb_b + Wc1@dec_emb_b
#define OFF_ENC   585728     // f16 [512][128]  enc_outs
#define OFF_HN    716800     // f32 [512][128]  final encoder hidden
// total ws used: 978944 bytes

typedef _Float16 f16_t;
typedef __attribute__((ext_vector_type(2))) _Float16 f16x2_t;

__device__ __forceinline__ float dot2f(uint32_t w, uint32_t a, float acc) {
#if __has_builtin(__builtin_amdgcn_fdot2)
  return __builtin_amdgcn_fdot2(__builtin_bit_cast(f16x2_t, w),
                                __builtin_bit_cast(f16x2_t, a), acc, false);
#else
  f16x2_t x = __builtin_bit_cast(f16x2_t, w);
  f16x2_t y = __builtin_bit_cast(f16x2_t, a);
  return acc + (float)x.x * (float)y.x + (float)x.y * (float)y.y;
#endif
}

__device__ __forceinline__ uint32_t pk2(float lo, float hi) {
#if __has_builtin(__builtin_amdgcn_cvt_pkrtz)
  return __builtin_bit_cast(uint32_t, __builtin_amdgcn_cvt_pkrtz(lo, hi));
#else
  f16x2_t v; v.x = (_Float16)lo; v.y = (_Float16)hi;
  return __builtin_bit_cast(uint32_t, v);
#endif
}

__device__ __forceinline__ float sigm(float x) { return 1.f / (1.f + __expf(-x)); }
// safe tanh: t->+inf => 1, t->-inf => -1 (no inf/inf)
__device__ __forceinline__ float tanh_s(float t) { float ex = __expf(2.f * t); return 1.f - 2.f / (ex + 1.f); }

#define LDS4(arr, idx) (*(const uint4*)&(arr)[(idx)])

// =====================================================================
// prep: weight folds + f16 conversions
// =====================================================================
__global__ void prep_kernel(const float* __restrict__ enc_emb_W, const float* __restrict__ enc_emb_b,
                            const float* __restrict__ enc_Wih, const float* __restrict__ enc_bih,
                            const float* __restrict__ dec_emb_W, const float* __restrict__ dec_emb_b,
                            const float* __restrict__ attn_W, const float* __restrict__ attn_b,
                            const float* __restrict__ comb_W, const float* __restrict__ comb_b,
                            const float* __restrict__ dec_Wih, const float* __restrict__ dec_Whh,
                            const float* __restrict__ enc_Whh, const float* __restrict__ out_W,
                            char* __restrict__ ws) {
  int t = blockIdx.x * 256 + threadIdx.x;
  if (t < 49152) {                       // M1 [384][128]
    int n = t >> 7, d = t & 127; float acc = 0.f;
    for (int h = 0; h < 128; ++h) acc += enc_Wih[n*128+h] * enc_emb_W[h*128+d];
    ((f16_t*)(ws+OFF_M1))[t] = (f16_t)acc; return;
  } t -= 49152;
  if (t < 384) {                         // bias_gi
    float acc = enc_bih[t];
    for (int h = 0; h < 128; ++h) acc += enc_Wih[t*128+h] * enc_emb_b[h];
    ((float*)(ws+OFF_BGI))[t] = acc; return;
  } t -= 384;
  if (t < 8192) {                        // P_a [512][16]
    int l = t >> 4, a = t & 15; float acc = 0.f;
    for (int k = 0; k < 128; ++k) acc += attn_W[l*256+k] * dec_emb_W[k*16+a];
    ((f16_t*)(ws+OFF_PA))[t] = (f16_t)acc; return;
  } t -= 8192;
  if (t < 512) {                         // zbias [512]
    float acc = attn_b[t];
    for (int k = 0; k < 128; ++k) acc += attn_W[t*256+k] * dec_emb_b[k];
    ((float*)(ws+OFF_ZB))[t] = acc; return;
  } t -= 512;
  if (t < 2048) {                        // P_c [128][16]
    int j = t >> 4, a = t & 15; float acc = 0.f;
    for (int k = 0; k < 128; ++k) acc += comb_W[j*256+k] * dec_emb_W[k*16+a];
    ((f16_t*)(ws+OFF_PC))[t] = (f16_t)acc; return;
  } t -= 2048;
  if (t < 128) {                         // obias [128]
    float acc = comb_b[t];
    for (int k = 0; k < 128; ++k) acc += comb_W[t*256+k] * dec_emb_b[k];
    ((float*)(ws+OFF_OB))[t] = acc; return;
  } t -= 128;
  if (t < 65536) {                       // Wb [512][128]
    int l = t >> 7, k = t & 127;
    ((f16_t*)(ws+OFF_WB))[t] = (f16_t)attn_W[l*256+128+k]; return;
  } t -= 65536;
  if (t < 49152) { ((f16_t*)(ws+OFF_WHHE))[t] = (f16_t)enc_Whh[t]; return; } t -= 49152;
  if (t < 49152) { ((f16_t*)(ws+OFF_WIH))[t]  = (f16_t)dec_Wih[t]; return; } t -= 49152;
  if (t < 49152) { ((f16_t*)(ws+OFF_WHH))[t]  = (f16_t)dec_Whh[t]; return; } t -= 49152;
  if (t < 16384) {                       // Wc2 [128][128]
    int j = t >> 7, k = t & 127;
    ((f16_t*)(ws+OFF_WC2))[t] = (f16_t)comb_W[j*256+128+k]; return;
  } t -= 16384;
  if (t < 2048) { ((f16_t*)(ws+OFF_OUTW))[t] = (f16_t)out_W[t]; return; }
}

// =====================================================================
// encoder: 256 blocks x 512 thr, rows (2b, 2b+1), 512 steps
// gi = obs@M1^T + bgi ; gh = h@WhhE^T + bhh ; GRU gates
// =====================================================================
__global__ __launch_bounds__(512, 2) void enc_kernel(const float* __restrict__ obs,
                                                     const float* __restrict__ enc_bhh,
                                                     char* __restrict__ ws) {
  __shared__ __align__(16) float    obs_s[2][H_];
  __shared__ __align__(16) uint32_t obspk[2][64];
  __shared__ __align__(16) float    gi_s[2][G3_];
  __shared__ __align__(16) float    gh_s[2][G3_];
  __shared__ __align__(16) float    hst[2][H_];
  __shared__ __align__(16) uint32_t hpk[2][64];
  __shared__ float bgi_s[G3_], bhh_s[G3_];

  const int tid = threadIdx.x, bid = blockIdx.x;
  const uint32_t* M1u  = (const uint32_t*)(ws + OFF_M1);
  const uint32_t* WHu  = (const uint32_t*)(ws + OFF_WHHE);
  const float*    bgi  = (const float*)(ws + OFF_BGI);
  f16_t* encw = (f16_t*)(ws + OFF_ENC);
  float* hN   = (float*)(ws + OFF_HN);

  uint32_t m1r[64], whr[64];
  if (tid < G3_) {
    const uint4* p1 = (const uint4*)(M1u + tid*64);
    const uint4* p2 = (const uint4*)(WHu + tid*64);
#pragma unroll
    for (int q = 0; q < 16; ++q) {
      uint4 v = p1[q]; m1r[q*4]=v.x; m1r[q*4+1]=v.y; m1r[q*4+2]=v.z; m1r[q*4+3]=v.w;
      uint4 w = p2[q]; whr[q*4]=w.x; whr[q*4+1]=w.y; whr[q*4+2]=w.z; whr[q*4+3]=w.w;
    }
    bgi_s[tid] = bgi[tid]; bhh_s[tid] = enc_bhh[tid];
  }
  if (tid < 256) hst[tid>>7][tid&127] = 0.f;
  if (tid < 128) hpk[tid>>6][tid&63] = 0u;
  __syncthreads();

#pragma unroll 1
  for (int t = 0; t < L_; ++t) {
    if (tid < 256) {
      int r = tid >> 7, d = tid & 127;
      obs_s[r][d] = obs[((size_t)(2*bid + r) * L_ + t) * H_ + d];
    }
    __syncthreads();
    if (tid < 128) {
      int r = tid >> 6, dp = tid & 63;
      obspk[r][dp] = pk2(obs_s[r][2*dp], obs_s[r][2*dp+1]);
    }
    __syncthreads();
    if (tid < G3_) {
      float g0 = bgi_s[tid], g1 = g0, ga = 0.f, gb = 0.f;
      float e0 = bhh_s[tid], e1 = e0, ea = 0.f, eb = 0.f;
#pragma unroll
      for (int c = 0; c < 16; ++c) {
        uint4 o0 = LDS4(obspk[0], c*4); uint4 o1 = LDS4(obspk[1], c*4);
        uint4 h0 = LDS4(hpk[0],  c*4);  uint4 h1 = LDS4(hpk[1],  c*4);
        g0 = dot2f(m1r[c*4+0], o0.x, g0); g0 = dot2f(m1r[c*4+1], o0.y, g0);
        ga = dot2f(m1r[c*4+2], o0.z, ga); ga = dot2f(m1r[c*4+3], o0.w, ga);
        g1 = dot2f(m1r[c*4+0], o1.x, g1); g1 = dot2f(m1r[c*4+1], o1.y, g1);
        gb = dot2f(m1r[c*4+2], o1.z, gb); gb = dot2f(m1r[c*4+3], o1.w, gb);
        e0 = dot2f(whr[c*4+0], h0.x, e0); e0 = dot2f(whr[c*4+1], h0.y, e0);
        ea = dot2f(whr[c*4+2], h0.z, ea); ea = dot2f(whr[c*4+3], h0.w, ea);
        e1 = dot2f(whr[c*4+0], h1.x, e1); e1 = dot2f(whr[c*4+1], h1.y, e1);
        eb = dot2f(whr[c*4+2], h1.z, eb); eb = dot2f(whr[c*4+3], h1.w, eb);
      }
      gi_s[0][tid] = g0+ga; gi_s[1][tid] = g1+gb;
      gh_s[0][tid] = e0+ea; gh_s[1][tid] = e1+eb;
    }
    __syncthreads();
    if (tid < 256) {
      int r = tid >> 7, jj = tid & 127;
      float ir = gi_s[r][jj], iz = gi_s[r][jj+128], in_ = gi_s[r][jj+256];
      float hr = gh_s[r][jj], hz = gh_s[r][jj+128], hn = gh_s[r][jj+256];
      float rg = sigm(ir + hr);
      float zg = sigm(iz + hz);
      float nn = tanh_s(in_ + rg * hn);
      float h2 = (1.f - zg) * nn + zg * hst[r][jj];
      hst[r][jj] = h2;
      if (bid == 0 && r == 0) encw[t*H_ + jj] = (f16_t)h2;
    }
    __syncthreads();
    if (tid < 128) {
      int r = tid >> 6, jp = tid & 63;
      hpk[r][jp] = pk2(hst[r][2*jp], hst[r][2*jp+1]);
    }
    __syncthreads();
  }
  if (tid < 256) {
    int r = tid >> 7, jj = tid & 127;
    hN[(2*bid + r)*H_ + jj] = hst[r][jj];
  }
}

// =====================================================================
// decoder: 256 blocks x 512 thr, rows (2b, 2b+1), 512 steps
// weights register-stationary (f16), enc_outs in LDS (interleaved)
// =====================================================================
__global__ __launch_bounds__(512, 2) void dec_kernel(const float* __restrict__ dec_bih,
                                                     const float* __restrict__ dec_bhh,
                                                     const float* __restrict__ out_b,
                                                     char* __restrict__ ws,
                                                     float* __restrict__ dout) {
  __shared__ __align__(16) uint32_t encI[64*128*4];    // 128KB: [c][k][q]
  __shared__ __align__(16) float    zarr[2][L_];       // 4KB (exp scratch)
  __shared__ __align__(16) uint32_t awpk[2][256];      // 2KB
  __shared__ __align__(16) float    aplred[2][4][H_];  // 4KB
  __shared__ __align__(16) uint32_t aplpk[2][64];      // 512B
  __shared__ __align__(16) float    gi_s[2][G3_];      // 3KB
  __shared__ __align__(16) float    gh_s[2][G3_];      // 3KB
  __shared__ __align__(16) float    otmp[2][H_];       // 1KB
  __shared__ __align__(16) uint32_t opk[2][64];        // 512B
  __shared__ __align__(16) float    hst[2][H_];        // 1KB
  __shared__ __align__(16) uint32_t hpk[2][64];        // 512B
  __shared__ __align__(16) uint32_t inppk[2][8];       // 64B
  __shared__ __align__(16) float    yred[2][A_][16];   // 2KB
  __shared__ float red_s[2][8];
  __shared__ float bih_s[G3_], bhh_s[G3_];
  __shared__ float ob_s[H_], outb_s[A_];

  const int tid = threadIdx.x, bid = blockIdx.x;
  const uint32_t* WBu  = (const uint32_t*)(ws + OFF_WB);
  const uint32_t* WIu  = (const uint32_t*)(ws + OFF_WIH);
  const uint32_t* WHu  = (const uint32_t*)(ws + OFF_WHH);
  const uint32_t* WCu  = (const uint32_t*)(ws + OFF_WC2);
  const uint32_t* PAu  = (const uint32_t*)(ws + OFF_PA);
  const uint32_t* PCu  = (const uint32_t*)(ws + OFF_PC);
  const uint32_t* OWu  = (const uint32_t*)(ws + OFF_OUTW);
  const float*    zb   = (const float*)(ws + OFF_ZB);
  const float*    obg  = (const float*)(ws + OFF_OB);
  const float*    hN   = (const float*)(ws + OFF_HN);

  // ---- register-stationary weights ----
  uint32_t wb[64], wA[64], wB[64];
  {
    const uint4* p = (const uint4*)(WBu + tid*64);
#pragma unroll
    for (int q = 0; q < 16; ++q) { uint4 v = p[q]; wb[q*4]=v.x; wb[q*4+1]=v.y; wb[q*4+2]=v.z; wb[q*4+3]=v.w; }
  }
  if (tid < G3_) {
    const uint4* p = (const uint4*)(WIu + tid*64);
#pragma unroll
    for (int q = 0; q < 16; ++q) { uint4 v = p[q]; wA[q*4]=v.x; wA[q*4+1]=v.y; wA[q*4+2]=v.z; wA[q*4+3]=v.w; }
  } else {
    const uint4* p = (const uint4*)(WCu + (tid-384)*64);
#pragma unroll
    for (int q = 0; q < 16; ++q) { uint4 v = p[q]; wA[q*4]=v.x; wA[q*4+1]=v.y; wA[q*4+2]=v.z; wA[q*4+3]=v.w; }
  }
  if (tid >= 128) {
    const uint4* p = (const uint4*)(WHu + (tid-128)*64);
#pragma unroll
    for (int q = 0; q < 16; ++q) { uint4 v = p[q]; wB[q*4]=v.x; wB[q*4+1]=v.y; wB[q*4+2]=v.z; wB[q*4+3]=v.w; }
  } else {
#pragma unroll
    for (int q = 0; q < 64; ++q) wB[q] = 0u;
  }

  // ---- stage enc_outs into interleaved LDS layout ----
  {
    int k = tid & 127, ls = tid >> 7;
    const uint16_t* eg = (const uint16_t*)(ws + OFF_ENC);
    uint16_t* ei = (uint16_t*)encI;
    for (int cc = 0; cc < 16; ++cc) {
      int c = ls*16 + cc;
#pragma unroll
      for (int p = 0; p < 8; ++p) ei[(c*128 + k)*8 + p] = eg[(c*8 + p)*128 + k];
    }
  }
  if (tid < G3_) { bih_s[tid] = dec_bih[tid]; bhh_s[tid] = dec_bhh[tid]; }
  if (tid < H_)  ob_s[tid] = obg[tid];
  if (tid < A_)  outb_s[tid] = out_b[tid];
  if (tid < 256) { int r = tid>>7, jj = tid&127; hst[r][jj] = hN[(2*bid + r)*H_ + jj]; }
  if (tid < 16)  inppk[tid>>3][tid&7] = 0u;
  __syncthreads();
  if (tid < 128) { int r = tid>>6, jp = tid&63; hpk[r][jp] = pk2(hst[r][2*jp], hst[r][2*jp+1]); }
  __syncthreads();

  const float zbias = zb[tid];

#pragma unroll 1
  for (int t = 0; t < L_; ++t) {
    // ---------- P1: attention logits z[r][l], l = tid ----------
    float z0, z1;
    {
      float a0 = zbias, a1 = zbias, b0 = 0.f, b1 = 0.f;
#pragma unroll
      for (int c = 0; c < 16; ++c) {
        uint4 h0 = LDS4(hpk[0], c*4); uint4 h1 = LDS4(hpk[1], c*4);
        a0 = dot2f(wb[c*4+0], h0.x, a0); a0 = dot2f(wb[c*4+1], h0.y, a0);
        b0 = dot2f(wb[c*4+2], h0.z, b0); b0 = dot2f(wb[c*4+3], h0.w, b0);
        a1 = dot2f(wb[c*4+0], h1.x, a1); a1 = dot2f(wb[c*4+1], h1.y, a1);
        b1 = dot2f(wb[c*4+2], h1.z, b1); b1 = dot2f(wb[c*4+3], h1.w, b1);
      }
      const uint32_t* pa = PAu + tid*8;
      uint4 p0 = *(const uint4*)pa; uint4 p1 = *(const uint4*)(pa + 4);
      uint4 q0 = LDS4(inppk[0], 0), q0b = LDS4(inppk[0], 4);
      uint4 q1 = LDS4(inppk[1], 0), q1b = LDS4(inppk[1], 4);
      a0 = dot2f(p0.x, q0.x, a0); a0 = dot2f(p0.y, q0.y, a0);
      a0 = dot2f(p0.z, q0.z, a0); a0 = dot2f(p0.w, q0.w, a0);
      b0 = dot2f(p1.x, q0b.x, b0); b0 = dot2f(p1.y, q0b.y, b0);
      b0 = dot2f(p1.z, q0b.z, b0); b0 = dot2f(p1.w, q0b.w, b0);
      a1 = dot2f(p0.x, q1.x, a1); a1 = dot2f(p0.y, q1.y, a1);
      a1 = dot2f(p0.z, q1.z, a1); a1 = dot2f(p0.w, q1.w, a1);
      b1 = dot2f(p1.x, q1b.x, b1); b1 = dot2f(p1.y, q1b.y, b1);
      b1 = dot2f(p1.z, q1b.z, b1); b1 = dot2f(p1.w, q1b.w, b1);
      z0 = a0 + b0; z1 = a1 + b1;
    }
    // ---------- P2: softmax over l ----------
    float m0 = z0, m1 = z1;
#pragma unroll
    for (int off = 32; off; off >>= 1) {
      m0 = fmaxf(m0, __shfl_xor(m0, off));
      m1 = fmaxf(m1, __shfl_xor(m1, off));
    }
    int wv = tid >> 6, ln = tid & 63;
    if (ln == 0) { red_s[0][wv] = m0; red_s[1][wv] = m1; }
    __syncthreads();
#pragma unroll
    for (int i = 0; i < 8; ++i) { m0 = fmaxf(m0, red_s[0][i]); m1 = fmaxf(m1, red_s[1][i]); }
    float e0 = __expf(z0 - m0), e1 = __expf(z1 - m1);
    float s0 = e0, s1 = e1;
#pragma unroll
    for (int off = 32; off; off >>= 1) { s0 += __shfl_xor(s0, off); s1 += __shfl_xor(s1, off); }
    __syncthreads();                       // done reading max partials
    if (ln == 0) { red_s[0][wv] = s0; red_s[1][wv] = s1; }
    __syncthreads();
    s0 = 0.f; s1 = 0.f;
#pragma unroll
    for (int i = 0; i < 8; ++i) { s0 += red_s[0][i]; s1 += red_s[1][i]; }
    float is0 = 1.f / s0, is1 = 1.f / s1;
    zarr[0][tid] = e0 * is0; zarr[1][tid] = e1 * is1;
    __syncthreads();
    { int rr = tid >> 8, ii = tid & 255;
      awpk[rr][ii] = pk2(zarr[rr][2*ii], zarr[rr][2*ii+1]); }
    __syncthreads();
    // ---------- P3: applied = aw @ enc_outs ----------
    {
      int k = tid & 127, ls = tid >> 7;
      float a0 = 0.f, b0 = 0.f, a1 = 0.f, b1 = 0.f;
#pragma unroll
      for (int cc = 0; cc < 16; ++cc) {
        int c = ls*16 + cc;
        uint4 ev = *(const uint4*)&encI[(c*128 + k)*4];
        uint4 w0 = LDS4(awpk[0], c*4);
        uint4 w1 = LDS4(awpk[1], c*4);
        a0 = dot2f(ev.x, w0.x, a0); a0 = dot2f(ev.y, w0.y, a0);
        b0 = dot2f(ev.z, w0.z, b0); b0 = dot2f(ev.w, w0.w, b0);
        a1 = dot2f(ev.x, w1.x, a1); a1 = dot2f(ev.y, w1.y, a1);
        b1 = dot2f(ev.z, w1.z, b1); b1 = dot2f(ev.w, w1.w, b1);
      }
      aplred[0][ls][k] = a0 + b0; aplred[1][ls][k] = a1 + b1;
    }
    __syncthreads();
    if (tid < 128) {
      int r = tid >> 6, kp = tid & 63;
      float v0 = aplred[r][0][2*kp] + aplred[r][1][2*kp] + aplred[r][2][2*kp] + aplred[r][3][2*kp];
      float v1 = aplred[r][0][2*kp+1] + aplred[r][1][2*kp+1] + aplred[r][2][2*kp+1] + aplred[r][3][2*kp+1];
      aplpk[r][kp] = pk2(v0, v1);
    }
    __syncthreads();
    // ---------- P4: o = relu(inp@Pc^T + applied@Wc2^T + obias) ----------
    if (tid >= 384) {
      int jj = tid - 384;
      float o0 = ob_s[jj], o1 = o0, oa = 0.f, obb = 0.f;
#pragma unroll
      for (int c = 0; c < 16; ++c) {
        uint4 p0 = LDS4(aplpk[0], c*4); uint4 p1 = LDS4(aplpk[1], c*4);
        o0 = dot2f(wA[c*4+0], p0.x, o0); o0 = dot2f(wA[c*4+1], p0.y, o0);
        oa = dot2f(wA[c*4+2], p0.z, oa); oa = dot2f(wA[c*4+3], p0.w, oa);
        o1 = dot2f(wA[c*4+0], p1.x, o1); o1 = dot2f(wA[c*4+1], p1.y, o1);
        obb = dot2f(wA[c*4+2], p1.z, obb); obb = dot2f(wA[c*4+3], p1.w, obb);
      }
      const uint32_t* pc = PCu + jj*8;
      uint4 c0 = *(const uint4*)pc; uint4 c1 = *(const uint4*)(pc + 4);
      uint4 i0 = LDS4(inppk[0], 0), i0b = LDS4(inppk[0], 4);
      uint4 i1 = LDS4(inppk[1], 0), i1b = LDS4(inppk[1], 4);
      o0 = dot2f(c0.x, i0.x, o0); o0 = dot2f(c0.y, i0.y, o0);
      o0 = dot2f(c0.z, i0.z, o0); o0 = dot2f(c0.w, i0.w, o0);
      oa = dot2f(c1.x, i0b.x, oa); oa = dot2f(c1.y, i0b.y, oa);
      oa = dot2f(c1.z, i0b.z, oa); oa = dot2f(c1.w, i0b.w, oa);
      o1 = dot2f(c0.x, i1.x, o1); o1 = dot2f(c0.y, i1.y, o1);
      o1 = dot2f(c0.z, i1.z, o1); o1 = dot2f(c0.w, i1.w, o1);
      obb = dot2f(c1.x, i1b.x, obb); obb = dot2f(c1.y, i1b.y, obb);
      obb = dot2f(c1.z, i1b.z, obb); obb = dot2f(c1.w, i1b.w, obb);
      otmp[0][jj] = fmaxf(o0 + oa, 0.f);
      otmp[1][jj] = fmaxf(o1 + obb, 0.f);
    }
    __syncthreads();
    if (tid < 128) { int r = tid>>6, jp = tid&63; opk[r][jp] = pk2(otmp[r][2*jp], otmp[r][2*jp+1]); }
    __syncthreads();
    // ---------- P5: gi = o@Wih^T + bih ; gh = h@Whh^T + bhh ----------
    if (tid < G3_) {
      float g0 = bih_s[tid], g1 = g0, ga = 0.f, gb = 0.f;
#pragma unroll
      for (int c = 0; c < 16; ++c) {
        uint4 o0 = LDS4(opk[0], c*4); uint4 o1 = LDS4(opk[1], c*4);
        g0 = dot2f(wA[c*4+0], o0.x, g0); g0 = dot2f(wA[c*4+1], o0.y, g0);
        ga = dot2f(wA[c*4+2], o0.z, ga); ga = dot2f(wA[c*4+3], o0.w, ga);
        g1 = dot2f(wA[c*4+0], o1.x, g1); g1 = dot2f(wA[c*4+1], o1.y, g1);
        gb = dot2f(wA[c*4+2], o1.z, gb); gb = dot2f(wA[c*4+3], o1.w, gb);
      }
      gi_s[0][tid] = g0 + ga; gi_s[1][tid] = g1 + gb;
    }
    if (tid >= 128) {
      int n = tid - 128;
      float e0g = bhh_s[n], e1g = e0g, ea = 0.f, eb = 0.f;
#pragma unroll
      for (int c = 0; c < 16; ++c) {
        uint4 h0 = LDS4(hpk[0], c*4); uint4 h1 = LDS4(hpk[1], c*4);
        e0g = dot2f(wB[c*4+0], h0.x, e0g); e0g = dot2f(wB[c*4+1], h0.y, e0g);
        ea  = dot2f(wB[c*4+2], h0.z, ea);  ea  = dot2f(wB[c*4+3], h0.w, ea);
        e1g = dot2f(wB[c*4+0], h1.x, e1g); e1g = dot2f(wB[c*4+1], h1.y, e1g);
        eb  = dot2f(wB[c*4+2], h1.z, eb);  eb  = dot2f(wB[c*4+3], h1.w, eb);
      }
      gh_s[0][n] = e0g + ea; gh_s[1][n] = e1g + eb;
    }
    __syncthreads();
    // ---------- P6: GRU gates ----------
    if (tid < 256) {
      int r = tid >> 7, jj = tid & 127;
      float ir = gi_s[r][jj], iz = gi_s[r][jj+128], in_ = gi_s[r][jj+256];
      float hr = gh_s[r][jj], hz = gh_s[r][jj+128], hn = gh_s[r][jj+256];
      float rg = sigm(ir + hr);
      float zg = sigm(iz + hz);
      float nn = tanh_s(in_ + rg * hn);
      hst[r][jj] = (1.f - zg) * nn + zg * hst[r][jj];
    }
    __syncthreads();
    if (tid < 128) { int r = tid>>6, jp = tid&63; hpk[r][jp] = pk2(hst[r][2*jp], hst[r][2*jp+1]); }
    __syncthreads();
    // ---------- P7: y = h2@outW^T (partials over 16 k-slices) ----------
    {
      int rr = tid >> 8, a = (tid >> 4) & 15, ks = tid & 15;
      uint4 w = *(const uint4*)(OWu + a*64 + ks*4);
      uint4 hb = LDS4(hpk[rr], ks*4);
      float y = dot2f(w.x, hb.x, 0.f);
      y = dot2f(w.y, hb.y, y);
      y = dot2f(w.z, hb.z, y);
      y = dot2f(w.w, hb.w, y);
      yred[rr][a][ks] = y;
    }
    __syncthreads();
    // ---------- P8: log_softmax over A=16, feedback ----------
    if (tid < 32) {
      int rr = tid >> 4, a = tid & 15;
      float y = outb_s[a];
#pragma unroll
      for (int ks = 0; ks < 16; ++ks) y += yred[rr][a][ks];
      float m = y;
#pragma unroll
      for (int off = 8; off; off >>= 1) m = fmaxf(m, __shfl_xor(m, off));
      float e = __expf(y - m);
      float s = e;
#pragma unroll
      for (int off = 8; off; off >>= 1) s += __shfl_xor(s, off);
      float lsf = (y - m) - __logf(s);
      if (t == L_-1) dout[(2*bid + rr)*A_ + a] = lsf;
      float partner = __shfl_xor(lsf, 1);
      if (!(a & 1)) inppk[rr][a >> 1] = pk2(lsf, partner);
    }
    __syncthreads();
  }
}

// =====================================================================
extern "C" void kernel_launch(void* const* d_in, const int* in_sizes, int n_in,
                              void* d_out, int out_size, void* d_ws, size_t ws_size,
                              hipStream_t stream) {
  (void)in_sizes; (void)n_in; (void)out_size; (void)ws_size;
  const float* obs       = (const float*)d_in[0];
  const float* enc_emb_W = (const float*)d_in[1];
  const float* enc_emb_b = (const float*)d_in[2];
  const float* enc_Wih   = (const float*)d_in[3];
  const float* enc_Whh   = (const float*)d_in[4];
  const float* enc_bih   = (const float*)d_in[5];
  const float* enc_bhh   = (const float*)d_in[6];
  const float* dec_emb_W = (const float*)d_in[7];
  const float* dec_emb_b = (const float*)d_in[8];
  const float* attn_W    = (const float*)d_in[9];
  const float* attn_b    = (const float*)d_in[10];
  const float* comb_W    = (const float*)d_in[11];
  const float* comb_b    = (const float*)d_in[12];
  const float* dec_Wih   = (const float*)d_in[13];
  const float* dec_Whh   = (const float*)d_in[14];
  const float* dec_bih   = (const float*)d_in[15];
  const float* dec_bhh   = (const float*)d_in[16];
  const float* out_W     = (const float*)d_in[17];
  const float* out_b     = (const float*)d_in[18];
  char* ws = (char*)d_ws;

  hipLaunchKernelGGL(prep_kernel, dim3(1140), dim3(256), 0, stream,
                     enc_emb_W, enc_emb_b, enc_Wih, enc_bih, dec_emb_W, dec_emb_b,
                     attn_W, attn_b, comb_W, comb_b, dec_Wih, dec_Whh, enc_Whh, out_W, ws);
  hipLaunchKernelGGL(enc_kernel, dim3(256), dim3(512), 0, stream, obs, enc_bhh, ws);
  hipLaunchKernelGGL(dec_kernel, dim3(256), dim3(512), 0, stream,
                     dec_bih, dec_bhh, out_b, ws, (float*)d_out);
}